// Round 1
// baseline (205.270 us; speedup 1.0000x reference)
//
#include <hip/hip_runtime.h>

// YOLO loss, round 7: LDS-staged, line-granularity gated, coalesced loads.
//
// r6 evidence: 59.6us, FETCH 72.6MB, 1.25 TB/s (15.6%), VALUBusy 8.4%,
// occupancy 57% -> neither BW- nor compute-bound. The kernel is
// transaction-bound: every load (pred float2 @120B stride, tcls float4
// @80B stride) is fully lane-diverged -> ~64 line-transactions per wave
// instruction, ~1.5k per wave, serialized in TA/TCP. Byte-gating (r6)
// cut bytes 2.4x but time only 12% -> transactions are the cost.
//
// r7 structure:
//  - pred tile (256 cells x 120B = 30KB) staged to LDS via LINEAR float4
//    copies (lane-contiguous, 16 lines/wave-instr). Each float4 gated at
//    line granularity: load iff an overlapping cell has mask=1, or it
//    contains comp 4 / comp 9 (only floats a mask=0 cell needs).
//  - tcls consumed TRANSPOSED (thread <-> linear float4 id, cell=q/5):
//    unit-stride global read, per-lane gated on smask[q/5]; pred side
//    comes from LDS. Skipped cells' lines are never requested.
//  - tbox: per-lane float4 (16B stride, 4 cells/line), gated on mask.
// Expected: FETCH ~100MB (up, intended), ~6x fewer transactions,
// dur ~20-26us.

#define SS 28
#define BLOCK 256
#define TILE 256                      // cells per block
#define NP4 (TILE * 30 / 4)           // 1920 pred float4 per tile
#define NT4 (TILE * 5)                // 1280 tcls float4 per tile

__global__ __launch_bounds__(BLOCK) void yolo_main(
    const float4* __restrict__ pred4,   // [cells*30/4]
    const float4* __restrict__ tbox4,   // [cells]
    const float4* __restrict__ tcls4,   // [cells*5]
    const int*   __restrict__ mask,     // [cells]
    float4* __restrict__ block_part,    // [gridDim.x]
    int cells)
{
    __shared__ float spred[TILE * 30];          // 30720 B
    __shared__ int   smask[TILE];               // 1024 B
    __shared__ float4 sred[BLOCK / 64];

    const int tid   = threadIdx.x;
    const int tile0 = blockIdx.x * TILE;
    const int tcells = min(TILE, cells - tile0);

    // ---- Phase A: mask tile (coalesced 4B) ----
    if (tid < tcells) smask[tid] = mask[tile0 + tid];
    else              smask[tid] = 0;
    __syncthreads();

    // ---- Phase B: gated, coalesced pred staging ----
    // float4 p covers tile-floats [4p, 4p+3]; records are 30 floats (7.5
    // float4), so a float4 can straddle two cells (c0, c3).
    {
        const size_t base4 = (size_t)tile0 * 30 / 4;
        const size_t lim4  = (size_t)cells * 30 / 4;
        #pragma unroll
        for (int it = 0; it < (NP4 + BLOCK - 1) / BLOCK; ++it) {
            int p = tid + it * BLOCK;
            if (p >= NP4) break;
            int f0 = 4 * p;
            int c0 = f0 / 30;
            int c3 = (f0 + 3) / 30;
            bool need = (smask[c0] | smask[c3]) != 0;
            if (!need) {
                // confidence comps 4 / 9 live entirely inside c0's span here
                int comp0 = f0 - c0 * 30;
                need = (comp0 >= 1 && comp0 <= 4) || (comp0 >= 6 && comp0 <= 9);
            }
            if (need && (base4 + p) < lim4) {
                float4 v = pred4[base4 + p];
                spred[f0 + 0] = v.x; spred[f0 + 1] = v.y;
                spred[f0 + 2] = v.z; spred[f0 + 3] = v.w;
            }
        }
    }
    __syncthreads();

    float acc_cls = 0.f, acc_noobj = 0.f, acc_reg = 0.f, acc_cont = 0.f;

    // ---- Phase C: per-cell compute (pred from LDS, tbox gated direct) ----
    if (tid < tcells) {
        const float* pr = spred + tid * 30;
        bool m = smask[tid] != 0;
        if (!m) {
            float c1 = pr[4], c2 = pr[9];
            acc_noobj = c1 * c1 + c2 * c2;          // *0.5 in finalize
        } else {
            float4 tb = tbox4[tile0 + tid];         // 16B stride, mask-gated

            const float invS = 1.f / 28.f;
            float txc = tb.x * invS, tyc = tb.y * invS;
            float t0 = txc - 0.5f * tb.z, t1 = tyc - 0.5f * tb.w;
            float t2 = txc + 0.5f * tb.z, t3 = tyc + 0.5f * tb.w;
            float ta = (t2 - t0) * (t3 - t1);

            float b1xc = pr[0] * invS, b1yc = pr[1] * invS;
            float a0 = b1xc - 0.5f * pr[2], a1 = b1yc - 0.5f * pr[3];
            float a2 = b1xc + 0.5f * pr[2], a3 = b1yc + 0.5f * pr[3];
            float wx = fmaxf(fminf(a2, t2) - fmaxf(a0, t0), 0.f);
            float wy = fmaxf(fminf(a3, t3) - fmaxf(a1, t1), 0.f);
            float inter = wx * wy;
            float area1 = (a2 - a0) * (a3 - a1);
            float den = area1 + ta - inter;
            float iou1 = inter / (den > 0.f ? den : 1.f);

            float b2xc = pr[5] * invS, b2yc = pr[6] * invS;
            float c0 = b2xc - 0.5f * pr[7], c1 = b2yc - 0.5f * pr[8];
            float c2 = b2xc + 0.5f * pr[7], c3 = b2yc + 0.5f * pr[8];
            wx = fmaxf(fminf(c2, t2) - fmaxf(c0, t0), 0.f);
            wy = fmaxf(fminf(c3, t3) - fmaxf(c1, t1), 0.f);
            inter = wx * wy;
            float area2 = (c2 - c0) * (c3 - c1);
            den = area2 + ta - inter;
            float iou2 = inter / (den > 0.f ? den : 1.f);

            bool take1 = iou1 > iou2;
            float best_iou = take1 ? iou1 : iou2;
            float bbx = take1 ? pr[0] : pr[5];
            float bby = take1 ? pr[1] : pr[6];
            float bbw = take1 ? pr[2] : pr[7];
            float bbh = take1 ? pr[3] : pr[8];
            float bbc = take1 ? pr[4] : pr[9];

            float dx = bbx - tb.x, dy = bby - tb.y;
            float xy = dx * dx + dy * dy;

            float dw = sqrtf(bbw) - sqrtf(tb.z);    // mask==1: where() == value
            float dh = sqrtf(bbh) - sqrtf(tb.w);
            float wh = dw * dw + dh * dh;

            acc_reg = xy + wh;

            float dc = bbc - best_iou;
            acc_cont = dc * dc;
        }
    }

    // ---- Phase D: cls loss, transposed (unit-stride tcls, gated) ----
    {
        const size_t tbase4 = (size_t)tile0 * 5;
        #pragma unroll
        for (int it = 0; it < NT4 / BLOCK; ++it) {      // 5 iters exactly
            int q  = tid + it * BLOCK;
            int cl = q / 5;
            if (cl < tcells && smask[cl]) {
                float4 t = tcls4[tbase4 + q];
                int comp = q - cl * 5;
                const float* pp = spred + cl * 30 + 10 + comp * 4;
                float d0 = pp[0] - t.x, d1 = pp[1] - t.y;
                float d2 = pp[2] - t.z, d3 = pp[3] - t.w;
                acc_cls += d0 * d0 + d1 * d1 + d2 * d2 + d3 * d3;
            }
        }
    }

    // ---- wave + block reduction ----
    float4 v = make_float4(acc_cls, acc_noobj, acc_reg, acc_cont);
    #pragma unroll
    for (int off = 32; off >= 1; off >>= 1) {
        v.x += __shfl_down(v.x, off, 64);
        v.y += __shfl_down(v.y, off, 64);
        v.z += __shfl_down(v.z, off, 64);
        v.w += __shfl_down(v.w, off, 64);
    }
    int lane = threadIdx.x & 63;
    int wave = threadIdx.x >> 6;
    if (lane == 0) sred[wave] = v;
    __syncthreads();
    if (threadIdx.x == 0) {
        float4 r = sred[0];
        #pragma unroll
        for (int w = 1; w < BLOCK / 64; ++w) {
            r.x += sred[w].x; r.y += sred[w].y; r.z += sred[w].z; r.w += sred[w].w;
        }
        block_part[blockIdx.x] = r;
    }
}

__global__ __launch_bounds__(BLOCK) void yolo_final(
    const float4* __restrict__ part, int nparts, float* __restrict__ out, float invN)
{
    float4 v = make_float4(0.f, 0.f, 0.f, 0.f);
    for (int i = threadIdx.x; i < nparts; i += BLOCK) {
        float4 p = part[i];
        v.x += p.x; v.y += p.y; v.z += p.z; v.w += p.w;
    }
    #pragma unroll
    for (int off = 32; off >= 1; off >>= 1) {
        v.x += __shfl_down(v.x, off, 64);
        v.y += __shfl_down(v.y, off, 64);
        v.z += __shfl_down(v.z, off, 64);
        v.w += __shfl_down(v.w, off, 64);
    }
    __shared__ float4 sred[BLOCK / 64];
    int lane = threadIdx.x & 63;
    int wave = threadIdx.x >> 6;
    if (lane == 0) sred[wave] = v;
    __syncthreads();
    if (threadIdx.x == 0) {
        float4 r = sred[0];
        #pragma unroll
        for (int w = 1; w < BLOCK / 64; ++w) {
            r.x += sred[w].x; r.y += sred[w].y; r.z += sred[w].z; r.w += sred[w].w;
        }
        float cls    = r.x;
        float no_obj = 0.5f * r.y;   // L_NOOBJ
        float reg    = 5.0f * r.z;   // L_COORD
        float cont   = r.w;
        float total  = cls + no_obj + cont + reg;
        out[0] = total  * invN;
        out[1] = reg    * invN;
        out[2] = cont   * invN;
        out[3] = no_obj * invN;
        out[4] = cls    * invN;
    }
}

extern "C" void kernel_launch(void* const* d_in, const int* in_sizes, int n_in,
                              void* d_out, int out_size, void* d_ws, size_t ws_size,
                              hipStream_t stream) {
    const float* pred = (const float*)d_in[0];
    const float* tbox = (const float*)d_in[1];
    const float* tcls = (const float*)d_in[2];
    const int*   mask = (const int*)d_in[3];
    float* out = (float*)d_out;

    int cells = in_sizes[0] / 30;                 // N*S*S = 802816
    int n_img = cells / (SS * SS);                // N
    int nblocks = (cells + TILE - 1) / TILE;      // 3136

    float4* part = (float4*)d_ws;                 // nblocks * 16 bytes

    yolo_main<<<nblocks, BLOCK, 0, stream>>>(
        (const float4*)pred, (const float4*)tbox, (const float4*)tcls,
        mask, part, cells);
    yolo_final<<<1, BLOCK, 0, stream>>>(part, nblocks, out, 1.0f / (float)n_img);
}